// Round 11
// baseline (132.827 us; speedup 1.0000x reference)
//
#include <hip/hip_runtime.h>

typedef unsigned long long u64;

#define C_DIM 128
#define MAXN 128   // per-row unique-neighbor cap; deg ~ Binom(131072,1/4096): mean 32, max ~56

// k1: edge-bitmap build + wo transpose (both grid-stride, independent) +
// q,k,v = x @ W^T + b. 16 rows/block, 256 blocks, W staged in LDS
// (one 192KB read per block shared by 4 waves), 4j x 2r register tile.
__global__ __launch_bounds__(256, 2) void build_qkv_kernel(
    const int* __restrict__ ei, int E, u64* __restrict__ bm, int wpr,
    const float* __restrict__ x,
    const float* __restrict__ wq, const float* __restrict__ bq,
    const float* __restrict__ wk, const float* __restrict__ bk,
    const float* __restrict__ wv, const float* __restrict__ bv,
    const float* __restrict__ wo, float* __restrict__ woT,
    float* __restrict__ qo, float* __restrict__ ko, float* __restrict__ vo)
{
    const int ROWS = 16;
    const int WSTR = C_DIM + 4;               // 132: pad -> 2-way max conflict on b128 (free)
    __shared__ float xs[ROWS][C_DIM];         // 8 KB
    __shared__ float wt[C_DIM * WSTR];        // 66 KB, reused q/k/v
    int t = threadIdx.x;
    int n0 = blockIdx.x * ROWS;
    int stride = gridDim.x * 256;
    int tid = blockIdx.x * 256 + t;

    // ---- edge build: grid-stride (2 edges/thread) ----
    for (int e = tid; e < E; e += stride) {
        int r = ei[e], c = ei[E + e];
        atomicOr(&bm[(size_t)r * wpr + (c >> 6)], 1ull << (c & 63));
    }
    // ---- wo transpose: woT[c*128+j] = wo[j*128+c] (first 16384 threads) ----
    for (int e2 = tid; e2 < C_DIM * C_DIM; e2 += stride) {
        int c = e2 >> 7, j = e2 & 127;
        woT[e2] = wo[j * C_DIM + c];
    }

    // ---- stage x rows ----
    #pragma unroll
    for (int i = 0; i < 2; ++i) {
        int g = t + i * 256;                  // float4 id over 512
        int r = g >> 5, c4 = (g & 31) << 2;
        *(float4*)&xs[r][c4] = *(const float4*)(x + (size_t)(n0 + r) * C_DIM + c4);
    }
    int jg = t & 31;                          // j = jg + 32*jj
    int r0 = (t >> 5) * 2;
    const float* Wp[3] = {wq, wk, wv};
    const float* Bp[3] = {bq, bk, bv};
    float*       Op[3] = {qo, ko, vo};
    for (int s = 0; s < 3; ++s) {
        __syncthreads();                      // previous-pass readers done (covers xs too)
        const float* W = Wp[s];
        #pragma unroll
        for (int i = 0; i < 16; ++i) {
            int g = t + i * 256;              // float4 id over 4096
            int j = g >> 5, c4 = (g & 31) << 2;
            *(float4*)&wt[j * WSTR + c4] = *(const float4*)(W + (size_t)j * C_DIM + c4);
        }
        __syncthreads();
        const float* B = Bp[s];
        float acc[4][2];
        #pragma unroll
        for (int jj = 0; jj < 4; ++jj) {
            float b = B[jg + jj * 32];
            acc[jj][0] = b; acc[jj][1] = b;
        }
        for (int c = 0; c < C_DIM; c += 4) {
            float4 xa = *(const float4*)&xs[r0][c];
            float4 xb = *(const float4*)&xs[r0 + 1][c];
            #pragma unroll
            for (int jj = 0; jj < 4; ++jj) {
                float4 w4 = *(const float4*)&wt[(jg + jj * 32) * WSTR + c];
                acc[jj][0] += w4.x * xa.x + w4.y * xa.y + w4.z * xa.z + w4.w * xa.w;
                acc[jj][1] += w4.x * xb.x + w4.y * xb.y + w4.z * xb.z + w4.w * xb.w;
            }
        }
        float* O = Op[s];
        #pragma unroll
        for (int jj = 0; jj < 4; ++jj) {
            int j = jg + jj * 32;
            O[(size_t)(n0 + r0) * C_DIM + j]     = acc[jj][0];
            O[(size_t)(n0 + r0 + 1) * C_DIM + j] = acc[jj][1];
        }
    }
}

// k2: attention (wave = row, 8 rows/block, 512 blocks, 512 threads)
// + oproj + residual + LN. Scoring: lane = (neighbor mod 16, head) -> 16
// neighbors in flight, no reductions. PV: lane = dim, chunk 16. ao in LDS.
__global__ __launch_bounds__(512, 4) void attn_oln_kernel(
    const float* __restrict__ q, const float* __restrict__ k,
    const float* __restrict__ v, const u64* __restrict__ bm, int wpr,
    const float* __restrict__ x,
    const float* __restrict__ woT, const float* __restrict__ bo,
    const float* __restrict__ gamma, const float* __restrict__ beta,
    float* __restrict__ out)
{
    const int ROWS = 8;
    __shared__ float qs[ROWS][C_DIM];    // 4 KB  (q row, scale pre-folded)
    __shared__ float xs[ROWS][C_DIM];    // 4 KB  (ao, then y)
    __shared__ int   lm[ROWS][MAXN];     // 4 KB  (per-wave neighbor list)
    __shared__ float ls[ROWS][4][MAXN];  // 16 KB (per-wave per-head scores/exp)
    int t = threadIdx.x;
    int n0 = blockIdx.x * ROWS;
    int wave = t >> 6, lane = t & 63;
    const float scale = 0.17677669529663687f;   // 1/sqrt(32)

    int n = n0 + wave;                   // this wave's row
    qs[wave][lane]      = q[(size_t)n * C_DIM + lane] * scale;
    qs[wave][64 + lane] = q[(size_t)n * C_DIM + 64 + lane] * scale;
    // ---- neighbor list from bitmap row (64 u64 words, one per lane) ----
    u64 bits = bm[(size_t)n * wpr + lane];
    int pc = __popcll(bits);
    int incl = pc;
    #pragma unroll
    for (int off = 1; off < 64; off <<= 1) {
        int tv = __shfl_up(incl, off);
        if (lane >= off) incl += tv;
    }
    int cnt = __shfl(incl, 63);
    int pos = incl - pc;
    u64 bb = bits;
    while (bb) {
        int b = __builtin_ctzll(bb);
        bb &= bb - 1;
        if (pos < MAXN) lm[wave][pos] = (lane << 6) + b;
        ++pos;
    }
    if (cnt > MAXN) cnt = MAXN;
    __syncthreads();
    // ---- scoring: lane = (nb, head); 16 neighbors per pass ----
    {
        int nb = lane & 15, hh = lane >> 4;
        float4 qf[8];
        #pragma unroll
        for (int u = 0; u < 8; ++u)
            qf[u] = *(const float4*)&qs[wave][hh * 32 + u * 4];
        for (int j0 = 0; j0 < cnt; j0 += 16) {
            int jj = j0 + nb;
            if (jj < cnt) {
                const float* kr = k + (size_t)lm[wave][jj] * C_DIM + hh * 32;
                float s = 0.f;
                #pragma unroll
                for (int u = 0; u < 8; ++u) {
                    float4 k4 = *(const float4*)(kr + u * 4);
                    s += qf[u].x * k4.x + qf[u].y * k4.y
                       + qf[u].z * k4.z + qf[u].w * k4.w;
                }
                ls[wave][hh][jj] = s;
            }
        }
    }
    __syncthreads();
    // ---- softmax: lane-group g (16 lanes) handles head g ----
    int g = lane >> 4, li = lane & 15;
    float mx = -1e30f;
    for (int jj = li; jj < cnt; jj += 16) mx = fmaxf(mx, ls[wave][g][jj]);
    #pragma unroll
    for (int off = 8; off; off >>= 1) mx = fmaxf(mx, __shfl_xor(mx, off));
    float sum = 0.f;
    for (int jj = li; jj < cnt; jj += 16) {
        float e = __expf(ls[wave][g][jj] - mx);
        ls[wave][g][jj] = e;
        sum += e;
    }
    #pragma unroll
    for (int off = 8; off; off >>= 1) sum += __shfl_xor(sum, off);
    float sinv = 1.0f / sum;     // >=1 neighbor (self-loop)
    __syncthreads();
    // ---- PV: lane d covers dims d and 64+d; chunk 16 ----
    int h0 = lane >> 5;          // head of dim lane (0/1); dim 64+lane -> h0+2
    float s0 = __shfl(sinv, h0 * 16);
    float s1 = __shfl(sinv, (h0 + 2) * 16);
    float a0 = 0.f, a1 = 0.f;
    for (int j0 = 0; j0 < cnt; j0 += 16) {
        int cc = cnt - j0; if (cc > 16) cc = 16;
        float v0a[16], v1a[16];
        #pragma unroll
        for (int u = 0; u < 16; ++u) {
            if (u < cc) {
                int m = lm[wave][j0 + u];
                v0a[u] = v[(size_t)m * C_DIM + lane];
                v1a[u] = v[(size_t)m * C_DIM + 64 + lane];
            }
        }
        #pragma unroll
        for (int u = 0; u < 16; ++u) {
            if (u < cc) {
                a0 += ls[wave][h0][j0 + u] * v0a[u];      // broadcast LDS read
                a1 += ls[wave][h0 + 2][j0 + u] * v1a[u];
            }
        }
    }
    xs[wave][lane]      = a0 * s0;
    xs[wave][64 + lane] = a1 * s1;
    __syncthreads();
    // ---- oproj: y[r][j] = sum_c ao[r][c]*woT[c][j] + bo[j]; float2 cols/lane ----
    int r  = t >> 6;                     // row 0..7 (== wave)
    int j2 = (t & 63) << 1;              // cols j2, j2+1
    float2 acc = *(const float2*)(bo + j2);
    #pragma unroll 2
    for (int c = 0; c < C_DIM; c += 4) {
        #pragma unroll
        for (int u = 0; u < 4; ++u) {
            float2 w2 = *(const float2*)(woT + (size_t)(c + u) * C_DIM + j2);
            float xv = xs[r][c + u];
            acc.x += xv * w2.x;
            acc.y += xv * w2.y;
        }
    }
    __syncthreads();   // all xs reads done before overwrite
    {   // residual, store y back to xs
        float2 xr = *(const float2*)(x + (size_t)(n0 + r) * C_DIM + j2);
        xs[r][j2]     = acc.x + xr.x;
        xs[r][j2 + 1] = acc.y + xr.y;
    }
    __syncthreads();
    // ---- LN: wave w handles row w ----
    {
        float y0 = xs[wave][lane], y1 = xs[wave][64 + lane];
        float s = y0 + y1, s2 = y0 * y0 + y1 * y1;
        #pragma unroll
        for (int off = 32; off; off >>= 1) {
            s  += __shfl_xor(s, off);
            s2 += __shfl_xor(s2, off);
        }
        float mu = s * (1.0f / 128.0f);
        float var = s2 * (1.0f / 128.0f) - mu * mu;
        float rstd = rsqrtf(var + 1e-5f);
        size_t o = (size_t)n * C_DIM;
        out[o + lane]      = (y0 - mu) * rstd * gamma[lane] + beta[lane];
        out[o + 64 + lane] = (y1 - mu) * rstd * gamma[64 + lane] + beta[64 + lane];
    }
}

extern "C" void kernel_launch(void* const* d_in, const int* in_sizes, int n_in,
                              void* d_out, int out_size, void* d_ws, size_t ws_size,
                              hipStream_t stream)
{
    const float* x     = (const float*)d_in[0];
    const int*   ei    = (const int*)d_in[1];
    const float* wq    = (const float*)d_in[2];
    const float* bq    = (const float*)d_in[3];
    const float* wk    = (const float*)d_in[4];
    const float* bk    = (const float*)d_in[5];
    const float* wv    = (const float*)d_in[6];
    const float* bv    = (const float*)d_in[7];
    const float* wo    = (const float*)d_in[8];
    const float* bo    = (const float*)d_in[9];
    const float* gamma = (const float*)d_in[10];
    const float* beta  = (const float*)d_in[11];
    float* out = (float*)d_out;

    int N = in_sizes[0] / C_DIM;   // 4096
    int E = in_sizes[1] / 2;       // 131072
    int wpr = N >> 6;              // u64 words per bitmap row (64)

    size_t mat_bytes = (size_t)N * C_DIM * sizeof(float);  // 2 MiB each
    char* base = (char*)d_ws;
    float* q   = (float*)(base);
    float* k   = (float*)(base + mat_bytes);
    float* v   = (float*)(base + 2 * mat_bytes);
    u64*   bm  = (u64*)(base + 3 * mat_bytes);             // N*N bits = 2 MiB
    float* woT = (float*)(base + 4 * mat_bytes);           // 64 KB

    hipMemsetAsync(bm, 0, (size_t)N * wpr * sizeof(u64), stream);
    build_qkv_kernel<<<N / 16, 256, 0, stream>>>(ei, E, bm, wpr,
                                                 x, wq, bq, wk, bk, wv, bv,
                                                 wo, woT, q, k, v);
    attn_oln_kernel<<<N / 8, 512, 0, stream>>>(q, k, v, bm, wpr,
                                               x, woT, bo, gamma, beta, out);
}

// Round 14
// 130.414 us; speedup vs baseline: 1.0185x; 1.0185x over previous
//
#include <hip/hip_runtime.h>

typedef unsigned long long u64;

#define C_DIM 128
#define MAXN 128   // per-row unique-neighbor cap; deg ~ Binom(131072,1/4096): mean 32, max ~56
#define WSTR (C_DIM + 4)   // 132: padded LDS leading dim

// k1: edge-bitmap build + wo transpose + q,k,v = x @ W^T + b.
// 8 rows/block, 512 threads, 512 blocks -> 70KB LDS, 2 blocks/CU, 16 waves/CU.
// Wave = row; each thread computes cols jg and jg+64 of its row.
__global__ __launch_bounds__(512, 4) void build_qkv_kernel(
    const int* __restrict__ ei, int E, u64* __restrict__ bm, int wpr,
    const float* __restrict__ x,
    const float* __restrict__ wq, const float* __restrict__ bq,
    const float* __restrict__ wk, const float* __restrict__ bk,
    const float* __restrict__ wv, const float* __restrict__ bv,
    const float* __restrict__ wo, float* __restrict__ woT,
    float* __restrict__ qo, float* __restrict__ ko, float* __restrict__ vo)
{
    const int ROWS = 8;
    __shared__ float xs[ROWS][C_DIM];         // 4 KB
    __shared__ float wt[C_DIM * WSTR];        // 66 KB, reused q/k/v
    int t = threadIdx.x;
    int n0 = blockIdx.x * ROWS;
    int tid = blockIdx.x * 512 + t;
    int nth = gridDim.x * 512;                // 262144

    // ---- edge build: one edge per thread (nth >= E) ----
    if (tid < E) {
        int r = ei[tid], c = ei[E + tid];
        atomicOr(&bm[(size_t)r * wpr + (c >> 6)], 1ull << (c & 63));
    }
    // ---- wo transpose: woT[c*128+j] = wo[j*128+c] ----
    for (int i = tid; i < C_DIM * C_DIM; i += nth) {
        int c = i >> 7, j = i & 127;
        woT[i] = wo[j * C_DIM + c];
    }

    // ---- stage x rows (256 float4) ----
    if (t < 256) {
        int r = t >> 5, c4 = (t & 31) << 2;
        *(float4*)&xs[r][c4] = *(const float4*)(x + (size_t)(n0 + r) * C_DIM + c4);
    }
    int row = t >> 6;                         // 0..7 (wave = row)
    int jg  = t & 63;                         // cols jg, jg+64
    const float* Wp[3] = {wq, wk, wv};
    const float* Bp[3] = {bq, bk, bv};
    float*       Op[3] = {qo, ko, vo};
    for (int s = 0; s < 3; ++s) {
        __syncthreads();                      // prev-pass readers done (covers xs)
        const float* W = Wp[s];
        #pragma unroll
        for (int i = 0; i < 8; ++i) {         // stage W: 4096 float4 / 512 thr
            int g = t + i * 512;
            int j = g >> 5, c4 = (g & 31) << 2;
            *(float4*)&wt[j * WSTR + c4] = *(const float4*)(W + (size_t)j * C_DIM + c4);
        }
        __syncthreads();
        const float* B = Bp[s];
        float acc0 = B[jg], acc1 = B[jg + 64];
        for (int c = 0; c < C_DIM; c += 4) {
            float4 xa = *(const float4*)&xs[row][c];            // wave-uniform (broadcast)
            float4 w0 = *(const float4*)&wt[jg * WSTR + c];
            float4 w1 = *(const float4*)&wt[(jg + 64) * WSTR + c];
            acc0 += w0.x * xa.x + w0.y * xa.y + w0.z * xa.z + w0.w * xa.w;
            acc1 += w1.x * xa.x + w1.y * xa.y + w1.z * xa.z + w1.w * xa.w;
        }
        float* O = Op[s];
        size_t o = (size_t)(n0 + row) * C_DIM;
        O[o + jg]      = acc0;
        O[o + jg + 64] = acc1;
    }
}

// k2: attention (wave = row, 8 rows/block, 512 blocks, 512 threads)
// + oproj + residual + LN. Scoring: lane = (neighbor mod 16, head) -> 16
// neighbors in flight, no reductions. PV: lane = dim, chunk 16. ao in LDS.
__global__ __launch_bounds__(512, 4) void attn_oln_kernel(
    const float* __restrict__ q, const float* __restrict__ k,
    const float* __restrict__ v, const u64* __restrict__ bm, int wpr,
    const float* __restrict__ x,
    const float* __restrict__ woT, const float* __restrict__ bo,
    const float* __restrict__ gamma, const float* __restrict__ beta,
    float* __restrict__ out)
{
    const int ROWS = 8;
    __shared__ float qs[ROWS][C_DIM];    // 4 KB  (q row, scale pre-folded)
    __shared__ float xs[ROWS][C_DIM];    // 4 KB  (ao, then y)
    __shared__ int   lm[ROWS][MAXN];     // 4 KB  (per-wave neighbor list)
    __shared__ float ls[ROWS][4][MAXN];  // 16 KB (per-wave per-head scores/exp)
    int t = threadIdx.x;
    int n0 = blockIdx.x * ROWS;
    int wave = t >> 6, lane = t & 63;
    const float scale = 0.17677669529663687f;   // 1/sqrt(32)

    int n = n0 + wave;                   // this wave's row
    qs[wave][lane]      = q[(size_t)n * C_DIM + lane] * scale;
    qs[wave][64 + lane] = q[(size_t)n * C_DIM + 64 + lane] * scale;
    // ---- neighbor list from bitmap row (64 u64 words, one per lane) ----
    u64 bits = bm[(size_t)n * wpr + lane];
    int pc = __popcll(bits);
    int incl = pc;
    #pragma unroll
    for (int off = 1; off < 64; off <<= 1) {
        int tv = __shfl_up(incl, off);
        if (lane >= off) incl += tv;
    }
    int cnt = __shfl(incl, 63);
    int pos = incl - pc;
    u64 bb = bits;
    while (bb) {
        int b = __builtin_ctzll(bb);
        bb &= bb - 1;
        if (pos < MAXN) lm[wave][pos] = (lane << 6) + b;
        ++pos;
    }
    if (cnt > MAXN) cnt = MAXN;
    __syncthreads();
    // ---- scoring: lane = (nb, head); 16 neighbors per pass ----
    {
        int nb = lane & 15, hh = lane >> 4;
        float4 qf[8];
        #pragma unroll
        for (int u = 0; u < 8; ++u)
            qf[u] = *(const float4*)&qs[wave][hh * 32 + u * 4];
        for (int j0 = 0; j0 < cnt; j0 += 16) {
            int jj = j0 + nb;
            if (jj < cnt) {
                const float* kr = k + (size_t)lm[wave][jj] * C_DIM + hh * 32;
                float s = 0.f;
                #pragma unroll
                for (int u = 0; u < 8; ++u) {
                    float4 k4 = *(const float4*)(kr + u * 4);
                    s += qf[u].x * k4.x + qf[u].y * k4.y
                       + qf[u].z * k4.z + qf[u].w * k4.w;
                }
                ls[wave][hh][jj] = s;
            }
        }
    }
    __syncthreads();
    // ---- softmax: lane-group g (16 lanes) handles head g ----
    int g = lane >> 4, li = lane & 15;
    float mx = -1e30f;
    for (int jj = li; jj < cnt; jj += 16) mx = fmaxf(mx, ls[wave][g][jj]);
    #pragma unroll
    for (int off = 8; off; off >>= 1) mx = fmaxf(mx, __shfl_xor(mx, off));
    float sum = 0.f;
    for (int jj = li; jj < cnt; jj += 16) {
        float e = __expf(ls[wave][g][jj] - mx);
        ls[wave][g][jj] = e;
        sum += e;
    }
    #pragma unroll
    for (int off = 8; off; off >>= 1) sum += __shfl_xor(sum, off);
    float sinv = 1.0f / sum;     // >=1 neighbor (self-loop)
    __syncthreads();
    // ---- PV: lane d covers dims d and 64+d; chunk 16 ----
    int h0 = lane >> 5;          // head of dim lane (0/1); dim 64+lane -> h0+2
    float s0 = __shfl(sinv, h0 * 16);
    float s1 = __shfl(sinv, (h0 + 2) * 16);
    float a0 = 0.f, a1 = 0.f;
    for (int j0 = 0; j0 < cnt; j0 += 16) {
        int cc = cnt - j0; if (cc > 16) cc = 16;
        float v0a[16], v1a[16];
        #pragma unroll
        for (int u = 0; u < 16; ++u) {
            if (u < cc) {
                int m = lm[wave][j0 + u];
                v0a[u] = v[(size_t)m * C_DIM + lane];
                v1a[u] = v[(size_t)m * C_DIM + 64 + lane];
            }
        }
        #pragma unroll
        for (int u = 0; u < 16; ++u) {
            if (u < cc) {
                a0 += ls[wave][h0][j0 + u] * v0a[u];      // broadcast LDS read
                a1 += ls[wave][h0 + 2][j0 + u] * v1a[u];
            }
        }
    }
    xs[wave][lane]      = a0 * s0;
    xs[wave][64 + lane] = a1 * s1;
    __syncthreads();
    // ---- oproj: y[r][j] = sum_c ao[r][c]*woT[c][j] + bo[j]; float2 cols/lane ----
    int r  = t >> 6;                     // row 0..7 (== wave)
    int j2 = (t & 63) << 1;              // cols j2, j2+1
    float2 acc = *(const float2*)(bo + j2);
    #pragma unroll 2
    for (int c = 0; c < C_DIM; c += 4) {
        #pragma unroll
        for (int u = 0; u < 4; ++u) {
            float2 w2 = *(const float2*)(woT + (size_t)(c + u) * C_DIM + j2);
            float xv = xs[r][c + u];
            acc.x += xv * w2.x;
            acc.y += xv * w2.y;
        }
    }
    __syncthreads();   // all xs reads done before overwrite
    {   // residual, store y back to xs
        float2 xr = *(const float2*)(x + (size_t)(n0 + r) * C_DIM + j2);
        xs[r][j2]     = acc.x + xr.x;
        xs[r][j2 + 1] = acc.y + xr.y;
    }
    __syncthreads();
    // ---- LN: wave w handles row w ----
    {
        float y0 = xs[wave][lane], y1 = xs[wave][64 + lane];
        float s = y0 + y1, s2 = y0 * y0 + y1 * y1;
        #pragma unroll
        for (int off = 32; off; off >>= 1) {
            s  += __shfl_xor(s, off);
            s2 += __shfl_xor(s2, off);
        }
        float mu = s * (1.0f / 128.0f);
        float var = s2 * (1.0f / 128.0f) - mu * mu;
        float rstd = rsqrtf(var + 1e-5f);
        size_t o = (size_t)n * C_DIM;
        out[o + lane]      = (y0 - mu) * rstd * gamma[lane] + beta[lane];
        out[o + 64 + lane] = (y1 - mu) * rstd * gamma[64 + lane] + beta[64 + lane];
    }
}

extern "C" void kernel_launch(void* const* d_in, const int* in_sizes, int n_in,
                              void* d_out, int out_size, void* d_ws, size_t ws_size,
                              hipStream_t stream)
{
    const float* x     = (const float*)d_in[0];
    const int*   ei    = (const int*)d_in[1];
    const float* wq    = (const float*)d_in[2];
    const float* bq    = (const float*)d_in[3];
    const float* wk    = (const float*)d_in[4];
    const float* bk    = (const float*)d_in[5];
    const float* wv    = (const float*)d_in[6];
    const float* bv    = (const float*)d_in[7];
    const float* wo    = (const float*)d_in[8];
    const float* bo    = (const float*)d_in[9];
    const float* gamma = (const float*)d_in[10];
    const float* beta  = (const float*)d_in[11];
    float* out = (float*)d_out;

    int N = in_sizes[0] / C_DIM;   // 4096
    int E = in_sizes[1] / 2;       // 131072
    int wpr = N >> 6;              // u64 words per bitmap row (64)

    size_t mat_bytes = (size_t)N * C_DIM * sizeof(float);  // 2 MiB each
    char* base = (char*)d_ws;
    float* q   = (float*)(base);
    float* k   = (float*)(base + mat_bytes);
    float* v   = (float*)(base + 2 * mat_bytes);
    u64*   bm  = (u64*)(base + 3 * mat_bytes);             // N*N bits = 2 MiB
    float* woT = (float*)(base + 4 * mat_bytes);           // 64 KB

    hipMemsetAsync(bm, 0, (size_t)N * wpr * sizeof(u64), stream);
    build_qkv_kernel<<<N / 8, 512, 0, stream>>>(ei, E, bm, wpr,
                                                x, wq, bq, wk, bk, wv, bv,
                                                wo, woT, q, k, v);
    attn_oln_kernel<<<N / 8, 512, 0, stream>>>(q, k, v, bm, wpr,
                                               x, woT, bo, gamma, beta, out);
}